// Round 12
// baseline (561.856 us; speedup 1.0000x reference)
//
#include <hip/hip_runtime.h>
#include <math.h>

// Problem constants
constexpr int N_  = 50000;
constexpr int E_  = 800000;
constexpr int H_  = 8;
constexpr int C_  = 16;
constexpr int HC_ = 128;
constexpr int ED_ = 16;        // E_DIM
constexpr int FF_ = 512;
constexpr float NEG_ = 0.2f;
constexpr float EPS_ = 1e-5f;
constexpr float LAMBDA_INIT_ = 0.8f;
constexpr float LOG2E_ = 1.4426950408889634f;

typedef __attribute__((ext_vector_type(8))) short bf16x8;
typedef __attribute__((ext_vector_type(4))) float f32x4;
typedef __fp16 half2v __attribute__((ext_vector_type(2)));

__device__ __forceinline__ float gelu_exact(float v) {
    return 0.5f * v * (1.0f + erff(v * 0.70710678118654752440f));
}
__device__ __forceinline__ ushort f2bf(float f) {  // RNE f32 -> bf16
    uint u = __float_as_uint(f);
    return (ushort)((u + 0x7FFFu + ((u >> 16) & 1u)) >> 16);
}
__device__ __forceinline__ ushort f2h(float f) {   // f32 -> f16 bits
    __fp16 h = (__fp16)f;
    return *(ushort*)&h;
}
__device__ __forceinline__ uint pkh2(float a, float b) {  // 2xf32 -> packed f16x2
    half2v h = __builtin_amdgcn_cvt_pkrtz(a, b);
    return *(uint*)&h;
}
__device__ __forceinline__ void uph2(uint u, float& a, float& b) {
    half2v h = *(half2v*)&u;
    a = (float)h.x; b = (float)h.y;
}

// ---------------- consolidated conversion kernel (+ degree histogram) ----------------
// ranges: x->bf16 | W_l12 (288 cols) | W_out^T | W_ff1^T | W_ff2^T(f16) | wc | lambda | hist
constexpr int XC_   = N_ * HC_ / 4;   // float4 items
constexpr int WL12_ = 288 * 128;
constexpr int WO_   = 128 * 128;
constexpr int WF1_  = 512 * 128;
constexpr int WF2_  = 128 * 512;
constexpr int CVT_TOTAL_ = XC_ + WL12_ + WO_ + WF1_ + WF2_ + 128 + 8 + E_;

__device__ void wconv(const float* __restrict__ W, ushort* __restrict__ Wt, int t, int K, int N) {
    int col = t / K, k = t - col * K;
    Wt[t] = f2bf(W[(size_t)k * N + col]);
}
__device__ void wconv_h(const float* __restrict__ W, ushort* __restrict__ Wt, int t, int K, int N) {
    int col = t / K, k = t - col * K;
    Wt[t] = f2h(W[(size_t)k * N + col]);
}

__global__ __launch_bounds__(256) void k_cvt(const float* __restrict__ x,
        const float* __restrict__ Wl1, const float* __restrict__ al1w, const float* __restrict__ ar1w,
        const float* __restrict__ Wl2, const float* __restrict__ al2w, const float* __restrict__ ar2w,
        const float* __restrict__ Wout, const float* __restrict__ Wff1, const float* __restrict__ Wff2,
        const float* __restrict__ We1, const float* __restrict__ ae1,
        const float* __restrict__ We2, const float* __restrict__ ae2,
        const float* __restrict__ lq1, const float* __restrict__ lk1,
        const float* __restrict__ lq2, const float* __restrict__ lk2,
        const int* __restrict__ dst0,
        ushort* __restrict__ xb, ushort* __restrict__ wl12t,
        ushort* __restrict__ woutt, ushort* __restrict__ wff1t, ushort* __restrict__ wff2t,
        float2* __restrict__ wc, float* __restrict__ lam,
        int* __restrict__ deg, int* __restrict__ rank) {
    int g = blockIdx.x * blockDim.x + threadIdx.x;
    if (g < XC_) {
        float4 v = ((const float4*)x)[g];
        ushort4 o;
        o.x = f2bf(v.x); o.y = f2bf(v.y); o.z = f2bf(v.z); o.w = f2bf(v.w);
        ((ushort4*)xb)[g] = o;
        return;
    }
    g -= XC_;
    if (g < WL12_) {
        int col = g >> 7, k = g & 127;
        const float* W = (col < 144) ? Wl1 : Wl2;
        const float* alw = (col < 144) ? al1w : al2w;
        const float* arw = (col < 144) ? ar1w : ar2w;
        int c = (col < 144) ? col : col - 144;
        float v;
        if (c < 128) {
            v = W[(size_t)k * HC_ + c];
        } else if (c < 136) {
            int h = c - 128; v = 0.f;
#pragma unroll
            for (int cc = 0; cc < 16; ++cc) v = fmaf(W[(size_t)k * HC_ + h * 16 + cc], alw[h * 16 + cc], v);
        } else {
            int h = c - 136; v = 0.f;
#pragma unroll
            for (int cc = 0; cc < 16; ++cc) v = fmaf(W[(size_t)k * HC_ + h * 16 + cc], arw[h * 16 + cc], v);
        }
        wl12t[g] = f2bf(v);
        return;
    }
    g -= WL12_;
    if (g < WO_) { wconv(Wout, woutt, g, 128, 128); return; }
    g -= WO_;
    if (g < WF1_) { wconv(Wff1, wff1t, g, 128, 512); return; }
    g -= WF1_;
    if (g < WF2_) { wconv_h(Wff2, wff2t, g, 512, 128); return; }
    g -= WF2_;
    if (g < 128) {  // wc[k*8+h] = (We1[k,:h]·ae1, We2[k,:h]·ae2)
        int k = g >> 3, h = g & 7;
        float s1 = 0.f, s2 = 0.f;
#pragma unroll
        for (int c = 0; c < 16; ++c) {
            s1 = fmaf(We1[k * HC_ + h * 16 + c], ae1[h * 16 + c], s1);
            s2 = fmaf(We2[k * HC_ + h * 16 + c], ae2[h * 16 + c], s2);
        }
        wc[g] = make_float2(s1, s2);
        return;
    }
    g -= 128;
    if (g < 8) {
        float d1 = 0.f, d2 = 0.f;
#pragma unroll
        for (int k = 0; k < 16; ++k) {
            d1 = fmaf(lq1[g * 16 + k], lk1[g * 16 + k], d1);
            d2 = fmaf(lq2[g * 16 + k], lk2[g * 16 + k], d2);
        }
        lam[g] = __expf(d1) - __expf(d2) + LAMBDA_INIT_;
        return;
    }
    g -= 8;
    if (g < E_) {  // degree histogram + per-edge rank
        rank[g] = atomicAdd(&deg[dst0[g]], 1);
    }
}

// ---------------- exclusive scan of deg -> offsets ----------------
__global__ __launch_bounds__(1024) void k_scan(const int* __restrict__ deg,
                                               int* __restrict__ offs) {
    __shared__ int part[1024];
    int t = threadIdx.x;
    const int CH = (N_ + 1023) / 1024;  // 49
    int b = t * CH;
    int e = min(N_, b + CH);
    int sum = 0;
    for (int i = b; i < e; ++i) sum += deg[i];
    part[t] = sum;
    __syncthreads();
    for (int off = 1; off < 1024; off <<= 1) {
        int v = (t >= off) ? part[t - off] : 0;
        __syncthreads();
        part[t] += v;
        __syncthreads();
    }
    int run = (t == 0) ? 0 : part[t - 1];
    for (int i = b; i < e; ++i) {
        offs[i] = run;
        run += deg[i];
    }
    if (t == 1023) offs[N_] = run;  // == E_
}

// ---------------- per-edge record builder + CSR fill ----------------
// p = offs[dst] + rank[e]; rec[p] (64B) = [8 x half2(a*log2e) | 8 x half2(ea)]; csr_src[p] = src.
__global__ __launch_bounds__(256) void k_et(const float* __restrict__ eattr,
                                            const float2* __restrict__ all_,
                                            const float2* __restrict__ arr_,
                                            const float2* __restrict__ wc,
                                            const int* __restrict__ offs,
                                            const int* __restrict__ rank,
                                            const int* __restrict__ src0,
                                            const int* __restrict__ dst0,
                                            uint* __restrict__ rec,
                                            int* __restrict__ csr_src) {
    __shared__ float2 wcs[128];
    int t = threadIdx.x;
    if (t < 128) wcs[t] = wc[t];
    __syncthreads();
    int e = blockIdx.x * blockDim.x + t;
    if (e >= E_) return;
    const float* ea = eattr + (size_t)e * ED_;
    float eav[16];
    {
        float4 q0 = *(const float4*)(ea + 0);
        float4 q1 = *(const float4*)(ea + 4);
        float4 q2 = *(const float4*)(ea + 8);
        float4 q3 = *(const float4*)(ea + 12);
        eav[0] = q0.x; eav[1] = q0.y; eav[2] = q0.z; eav[3] = q0.w;
        eav[4] = q1.x; eav[5] = q1.y; eav[6] = q1.z; eav[7] = q1.w;
        eav[8] = q2.x; eav[9] = q2.y; eav[10] = q2.z; eav[11] = q2.w;
        eav[12] = q3.x; eav[13] = q3.y; eav[14] = q3.z; eav[15] = q3.w;
    }
    int src = src0[e], dst = dst0[e];
    const float2* alp = all_ + (size_t)dst * 8;
    const float2* arp = arr_ + (size_t)src * 8;
    uint ra[8], re[8];
#pragma unroll
    for (int h = 0; h < 8; ++h) {
        float t1 = 0.f, t2 = 0.f;
#pragma unroll
        for (int k = 0; k < 16; ++k) {
            float2 w = wcs[k * 8 + h];
            t1 = fmaf(eav[k], w.x, t1);
            t2 = fmaf(eav[k], w.y, t2);
        }
        float2 al = alp[h], ar = arp[h];
        float a1 = al.x + ar.x + t1;
        a1 = ((a1 >= 0.f) ? a1 : NEG_ * a1) * LOG2E_;
        float a2 = al.y + ar.y + t2;
        a2 = ((a2 >= 0.f) ? a2 : NEG_ * a2) * LOG2E_;
        ra[h] = pkh2(a1, a2);
    }
#pragma unroll
    for (int i = 0; i < 8; ++i) re[i] = pkh2(eav[2 * i], eav[2 * i + 1]);
    int p = offs[dst] + rank[e];
    csr_src[p] = src;
    uint4* rp = (uint4*)(rec + (size_t)p * 16);
    rp[0] = make_uint4(ra[0], ra[1], ra[2], ra[3]);
    rp[1] = make_uint4(ra[4], ra[5], ra[6], ra[7]);
    rp[2] = make_uint4(re[0], re[1], re[2], re[3]);
    rp[3] = make_uint4(re[4], re[5], re[6], re[7]);
}

// ---------------- fused dual attention + diff combine + rmsnorm ----------------
__global__ __launch_bounds__(256) void k_agg(const ushort* __restrict__ x12,
                                             const float2* __restrict__ all_,
                                             const float2* __restrict__ arr_,
                                             const uint* __restrict__ rec,
                                             const float2* __restrict__ wcg,
                                             const float* __restrict__ We1, const float* __restrict__ We2,
                                             const float* __restrict__ lam, const float* __restrict__ rms_attn,
                                             const int* __restrict__ offs, const int* __restrict__ csr_src,
                                             ushort* __restrict__ attn_out) {
    int wid = (int)((blockIdx.x * blockDim.x + threadIdx.x) >> 6);
    if (wid >= N_) return;
    int lane = threadIdx.x & 63;
    int h = lane >> 3;
    int cp = lane & 7;
    int e0 = h * C_ + cp * 2;
    int hbase = lane & 56;

    int s = offs[wid], eend = offs[wid + 1];
    int deg = eend - s;

    float s1 = 0.f, s2 = 0.f;
    float ax1x = 0.f, ax1y = 0.f, ax2x = 0.f, ax2y = 0.f;
    float ws1x = 0.f, ws1y = 0.f, ws2x = 0.f, ws2y = 0.f;
    float esx = 0.f, esy = 0.f;

    auto edge_step = [&](int j) {
        int src = csr_src[j];
        const uint* r = rec + (size_t)j * 16;
        uint ua = r[h];
        uint ue = r[8 + cp];
        uint2 ux = *(const uint2*)(x12 + (size_t)src * 256 + e0 * 2);
        float a1, a2, eax, eay, x1a, x2a, x1b, x2b;
        uph2(ua, a1, a2);
        uph2(ue, eax, eay);
        uph2(ux.x, x1a, x2a);
        uph2(ux.y, x1b, x2b);
        float p1 = exp2f(a1), p2 = exp2f(a2);
        s1 += p1; s2 += p2;
        ax1x = fmaf(p1, x1a, ax1x); ax1y = fmaf(p1, x1b, ax1y);
        ax2x = fmaf(p2, x2a, ax2x); ax2y = fmaf(p2, x2b, ax2y);
        ws1x = fmaf(p1, eax, ws1x); ws1y = fmaf(p1, eay, ws1y);
        ws2x = fmaf(p2, eax, ws2x); ws2y = fmaf(p2, eay, ws2y);
        esx += eax; esy += eay;
    };

    int j = s;
    for (; j + 1 < eend; j += 2) {
        edge_step(j);
        edge_step(j + 1);
    }
    if (j < eend) edge_step(j);

    // ---- self-loop: ea_self = mean of incoming ea ----
    float invdeg = 1.0f / (float)max(deg, 1);
    float esmx = esx * invdeg, esmy = esy * invdeg;

    float2 w0 = wcg[(2 * cp) * 8 + h];
    float2 w1 = wcg[(2 * cp + 1) * 8 + h];
    float tp1 = esmx * w0.x + esmy * w1.x;
    float tp2 = esmx * w0.y + esmy * w1.y;
    tp1 += __shfl_xor(tp1, 1); tp1 += __shfl_xor(tp1, 2); tp1 += __shfl_xor(tp1, 4);
    tp2 += __shfl_xor(tp2, 1); tp2 += __shfl_xor(tp2, 2); tp2 += __shfl_xor(tp2, 4);

    float2 alv = all_[(size_t)wid * 8 + h];
    float2 arv = arr_[(size_t)wid * 8 + h];
    float aS1 = alv.x + arv.x + tp1;
    aS1 = ((aS1 >= 0.f) ? aS1 : NEG_ * aS1) * LOG2E_;
    float aS2 = alv.y + arv.y + tp2;
    aS2 = ((aS2 >= 0.f) ? aS2 : NEG_ * aS2) * LOG2E_;
    float pS1 = exp2f(aS1), pS2 = exp2f(aS2);
    {
        uint2 ux = *(const uint2*)(x12 + (size_t)wid * 256 + e0 * 2);
        float x1a, x2a, x1b, x2b;
        uph2(ux.x, x1a, x2a);
        uph2(ux.y, x1b, x2b);
        s1 += pS1; s2 += pS2;
        ax1x = fmaf(pS1, x1a, ax1x); ax1y = fmaf(pS1, x1b, ax1y);
        ax2x = fmaf(pS2, x2a, ax2x); ax2y = fmaf(pS2, x2b, ax2y);
        ws1x = fmaf(pS1, esmx, ws1x); ws1y = fmaf(pS1, esmy, ws1y);
        ws2x = fmaf(pS2, esmx, ws2x); ws2y = fmaf(pS2, esmy, ws2y);
    }

    // ---- final: out = (ax + ws @ We) / s ----
    float o1x = ax1x, o1y = ax1y, o2x = ax2x, o2y = ax2y;
#pragma unroll
    for (int kp = 0; kp < 8; ++kp) {
        float wa1 = __shfl(ws1x, hbase + kp), wb1 = __shfl(ws1y, hbase + kp);
        float wa2 = __shfl(ws2x, hbase + kp), wb2 = __shfl(ws2y, hbase + kp);
        float2 a0 = *(const float2*)(We1 + (2 * kp) * HC_ + e0);
        float2 a1 = *(const float2*)(We1 + (2 * kp + 1) * HC_ + e0);
        float2 b0 = *(const float2*)(We2 + (2 * kp) * HC_ + e0);
        float2 b1 = *(const float2*)(We2 + (2 * kp + 1) * HC_ + e0);
        o1x = fmaf(wa1, a0.x, o1x); o1x = fmaf(wb1, a1.x, o1x);
        o1y = fmaf(wa1, a0.y, o1y); o1y = fmaf(wb1, a1.y, o1y);
        o2x = fmaf(wa2, b0.x, o2x); o2x = fmaf(wb2, b1.x, o2x);
        o2y = fmaf(wa2, b0.y, o2y); o2y = fmaf(wb2, b1.y, o2y);
    }
    float inv1 = 1.0f / s1, inv2 = 1.0f / s2;
    o1x *= inv1; o1y *= inv1; o2x *= inv2; o2y *= inv2;

    float lamh = lam[h];
    float v0 = o1x - lamh * o2x;
    float v1 = o1y - lamh * o2y;

    float ss = v0 * v0 + v1 * v1;
#pragma unroll
    for (int mk = 1; mk < 64; mk <<= 1) ss += __shfl_xor(ss, mk);
    float rn = rsqrtf(ss * (1.0f / 128.0f) + EPS_);
    float g0 = rms_attn[e0] * (1.0f - LAMBDA_INIT_);
    float g1 = rms_attn[e0 + 1] * (1.0f - LAMBDA_INIT_);
    ushort2 o;
    o.x = f2bf(v0 * rn * g0);
    o.y = f2bf(v1 * rn * g1);
    *(ushort2*)(attn_out + (size_t)wid * HC_ + e0) = o;
}

// ---------------- bf16 MFMA GEMM, fused epilogues ----------------
// EPI 0: NT=18 (W_l1‖W_l2 + u-cols). ct<8 & ct+9 -> packed f16 x12; ct==8/17 -> al/ar float2.
// EPI 1: C f32 = acc+b1+b2+res; fused RMSNorm -> hn bf16 (N==128, grid.y==1).
template <int EPI>
__global__ __launch_bounds__(256) void k_gmm(const ushort* __restrict__ A,
                                             const ushort* __restrict__ Bt,
                                             void* __restrict__ Cv,
                                             int M, int N, int K,
                                             const float* __restrict__ b1,
                                             const float* __restrict__ b2,
                                             const float* __restrict__ res,
                                             const float* __restrict__ scale,
                                             ushort* __restrict__ out2,
                                             float2* __restrict__ alr,
                                             float2* __restrict__ arr) {
    constexpr int NT = (EPI == 0) ? 18 : 8;
    int tid = threadIdx.x;
    int w = tid >> 6, lane = tid & 63;
    int bm = blockIdx.x * 64 + w * 16;
    int lrow = lane & 15, kg = lane >> 4;

    f32x4 acc[NT];
#pragma unroll
    for (int i = 0; i < NT; ++i) acc[i] = (f32x4){0.f, 0.f, 0.f, 0.f};

    int arow = bm + lrow;
    const ushort* Ap = A + (size_t)min(arow, M - 1) * K + kg * 8;
    const ushort* Bp0 = Bt + (size_t)lrow * K + kg * 8;

    for (int ks = 0; ks < K; ks += 32) {
        bf16x8 af = *(const bf16x8*)(Ap + ks);
        const ushort* Bp = Bp0 + ks;
#pragma unroll
        for (int ct = 0; ct < NT; ++ct) {
            bf16x8 bf = *(const bf16x8*)(Bp + (size_t)ct * 16 * K);
            acc[ct] = __builtin_amdgcn_mfma_f32_16x16x32_bf16(af, bf, acc[ct], 0, 0, 0);
        }
    }

    if constexpr (EPI == 0) {
#pragma unroll
        for (int ct = 0; ct < 8; ++ct) {
            int col = ct * 16 + lrow;
#pragma unroll
            for (int jj = 0; jj < 4; ++jj) {
                int r = bm + kg * 4 + jj;
                if (r < M) ((uint*)Cv)[(size_t)r * 128 + col] = pkh2(acc[ct][jj], acc[ct + 9][jj]);
            }
        }
        int cc = lrow;
#pragma unroll
        for (int jj = 0; jj < 4; ++jj) {
            int r = bm + kg * 4 + jj;
            if (r < M) {
                float2 v = make_float2(acc[8][jj], acc[17][jj]);
                if (cc < 8) alr[(size_t)r * 8 + cc] = v;
                else        arr[(size_t)r * 8 + (cc - 8)] = v;
            }
        }
    } else {
        float ssj[4] = {0.f, 0.f, 0.f, 0.f};
#pragma unroll
        for (int ct = 0; ct < 8; ++ct) {
            int col = ct * 16 + lrow;
            float bv = b1[col] + b2[col];
#pragma unroll
            for (int jj = 0; jj < 4; ++jj) {
                int r = bm + kg * 4 + jj;
                if (r < M) {
                    float v = acc[ct][jj] + bv + res[(size_t)r * HC_ + col];
                    acc[ct][jj] = v;
                    ssj[jj] += v * v;
                }
            }
        }
        float rn[4];
#pragma unroll
        for (int jj = 0; jj < 4; ++jj) {
            float ss = ssj[jj];
            ss += __shfl_xor(ss, 1); ss += __shfl_xor(ss, 2);
            ss += __shfl_xor(ss, 4); ss += __shfl_xor(ss, 8);
            rn[jj] = rsqrtf(ss * (1.0f / 128.0f) + EPS_);
        }
#pragma unroll
        for (int ct = 0; ct < 8; ++ct) {
            int col = ct * 16 + lrow;
            float sc = scale[col];
#pragma unroll
            for (int jj = 0; jj < 4; ++jj) {
                int r = bm + kg * 4 + jj;
                if (r < M) {
                    float v = acc[ct][jj];
                    ((float*)Cv)[(size_t)r * HC_ + col] = v;
                    out2[(size_t)r * HC_ + col] = f2bf(v * rn[jj] * sc);
                }
            }
        }
    }
}

// ---------------- fused FFN: out = h + (gelu(hn@Wff1+b1))@Wff2 + b2 ----------------
// Split-K over FF: two halves of 256 cols; g half-tile (64x(256+8) f16, 33.8 KB) in LDS.
// 4 blocks/CU; padded stride kills the 512-stride bank pathology.
constexpr int GP_ = 8;  // LDS row pad (ushorts): stride 264 -> bank step 4 per row -> 2-way max
__global__ __launch_bounds__(256) void k_ffn(const ushort* __restrict__ hn,     // [N][128] bf16
                                             const ushort* __restrict__ wff1t,  // [512][128] bf16
                                             const ushort* __restrict__ wff2t,  // [128][512] f16
                                             const float* __restrict__ bff1,
                                             const float* __restrict__ bff2,
                                             const float* __restrict__ hres,    // [N][128] f32
                                             float* __restrict__ out) {
    __shared__ ushort g_lds[64][256 + GP_];
    int tid = threadIdx.x;
    int w = tid >> 6, lane = tid & 63;
    int bm = blockIdx.x * 64 + w * 16;
    int lrow = lane & 15, kg = lane >> 4;

    const ushort* Ap = hn + (size_t)min(bm + lrow, N_ - 1) * HC_ + kg * 8;

    f32x4 acc2[8];
#pragma unroll
    for (int i = 0; i < 8; ++i) acc2[i] = (f32x4){0.f, 0.f, 0.f, 0.f};

#pragma unroll
    for (int hf = 0; hf < 2; ++hf) {
        if (hf) __syncthreads();  // all waves done reading previous half
        // ---- ff1: cols hf*256 .. +255 (2 chunks of 128) -> gelu -> LDS ----
#pragma unroll
        for (int chunk = 0; chunk < 2; ++chunk) {
            f32x4 acc[8];
#pragma unroll
            for (int i = 0; i < 8; ++i) acc[i] = (f32x4){0.f, 0.f, 0.f, 0.f};
            const ushort* Bp0 = wff1t + (size_t)(hf * 256 + chunk * 128 + lrow) * HC_ + kg * 8;
#pragma unroll
            for (int ks = 0; ks < HC_; ks += 32) {
                bf16x8 af = *(const bf16x8*)(Ap + ks);
#pragma unroll
                for (int ct = 0; ct < 8; ++ct) {
                    bf16x8 bf = *(const bf16x8*)(Bp0 + ks + (size_t)ct * 16 * HC_);
                    acc[ct] = __builtin_amdgcn_mfma_f32_16x16x32_bf16(af, bf, acc[ct], 0, 0, 0);
                }
            }
#pragma unroll
            for (int ct = 0; ct < 8; ++ct) {
                int lcol = chunk * 128 + ct * 16 + lrow;
                float bv = bff1[hf * 256 + lcol];
#pragma unroll
                for (int jj = 0; jj < 4; ++jj) {
                    int r = w * 16 + kg * 4 + jj;
                    g_lds[r][lcol] = f2h(gelu_exact(acc[ct][jj] + bv));
                }
            }
        }
        __syncthreads();
        // ---- ff2 partial: K = hf*256 .. +255 (f16 MFMA) ----
        const ushort* gl = &g_lds[w * 16 + lrow][kg * 8];
        const ushort* Bp0 = wff2t + (size_t)lrow * FF_ + hf * 256 + kg * 8;
#pragma unroll
        for (int ks = 0; ks < 256; ks += 32) {
            bf16x8 af = *(const bf16x8*)(gl + ks);
#pragma unroll
            for (int ct = 0; ct < 8; ++ct) {
                bf16x8 bf = *(const bf16x8*)(Bp0 + ks + (size_t)ct * 16 * FF_);
                acc2[ct] = __builtin_amdgcn_mfma_f32_16x16x32_f16(af, bf, acc2[ct], 0, 0, 0);
            }
        }
    }

#pragma unroll
    for (int ct = 0; ct < 8; ++ct) {
        int col = ct * 16 + lrow;
        float bv = bff2[col];
#pragma unroll
        for (int jj = 0; jj < 4; ++jj) {
            int r = bm + kg * 4 + jj;
            if (r < N_) out[(size_t)r * HC_ + col] = acc2[ct][jj] + bv + hres[(size_t)r * HC_ + col];
        }
    }
}

extern "C" void kernel_launch(void* const* d_in, const int* in_sizes, int n_in,
                              void* d_out, int out_size, void* d_ws, size_t ws_size,
                              hipStream_t stream) {
    const float* x        = (const float*)d_in[0];
    const float* eattr    = (const float*)d_in[1];
    const float* W_l1     = (const float*)d_in[2];
    const float* W_l2     = (const float*)d_in[3];
    const float* att_l1   = (const float*)d_in[4];
    const float* att_r1   = (const float*)d_in[5];
    const float* att_l2   = (const float*)d_in[6];
    const float* att_r2   = (const float*)d_in[7];
    const float* W_e1     = (const float*)d_in[8];
    const float* att_e1   = (const float*)d_in[9];
    const float* W_e2     = (const float*)d_in[10];
    const float* att_e2   = (const float*)d_in[11];
    const float* lq1      = (const float*)d_in[12];
    const float* lk1      = (const float*)d_in[13];
    const float* lq2      = (const float*)d_in[14];
    const float* lk2      = (const float*)d_in[15];
    const float* rms_attn = (const float*)d_in[16];
    const float* W_out    = (const float*)d_in[17];
    const float* b_out    = (const float*)d_in[18];
    const float* bias_x   = (const float*)d_in[19];
    const float* rms_layer= (const float*)d_in[20];
    const float* W_ff1    = (const float*)d_in[21];
    const float* b_ff1    = (const float*)d_in[22];
    const float* W_ff2    = (const float*)d_in[23];
    const float* b_ff2    = (const float*)d_in[24];
    const int*   eidx     = (const int*)d_in[25];
    const int* src0 = eidx;
    const int* dst0 = eidx + E_;
    float* out = (float*)d_out;

    // ---- workspace layout ----
    char* base = (char*)d_ws;
    size_t off = 0;
    auto alloc = [&](size_t bytes) -> char* {
        off = (off + 255) & ~(size_t)255;
        char* p = base + off;
        off += bytes;
        return p;
    };
    const size_t NF = (size_t)N_ * HC_;
    float*  f_h    = (float*)alloc(NF * 4);
    ushort* f_hnat = (ushort*)alloc(NF * 2);        // attn bf16 then hn bf16
    ushort* f_x12  = (ushort*)alloc(NF * 2 * 2);    // interleaved f16 x1/x2 [N][256]
    uint*   f_rec  = (uint*)alloc((size_t)E_ * 64); // rec (64B/edge, CSR order)
    ushort* f_xb   = (ushort*)alloc(NF * 2);
    ushort* w_l12t = (ushort*)alloc((size_t)288 * 128 * 2);
    ushort* w_outt = (ushort*)alloc((size_t)HC_ * HC_ * 2);
    ushort* w_ff1t = (ushort*)alloc((size_t)HC_ * FF_ * 2);
    ushort* w_ff2t = (ushort*)alloc((size_t)FF_ * HC_ * 2);
    float2* f_all  = (float2*)alloc((size_t)N_ * H_ * 8);
    float2* f_arr  = (float2*)alloc((size_t)N_ * H_ * 8);
    float2* f_wc   = (float2*)alloc(128 * 8);
    float*  f_lam  = (float*)alloc(256);
    int*  i_deg  = (int*)alloc((size_t)N_ * 4);
    int*  i_offs = (int*)alloc((size_t)(N_ + 1) * 4);
    int*  i_rank = (int*)alloc((size_t)E_ * 4);
    int*  i_csr  = (int*)alloc((size_t)E_ * 4);
    (void)ws_size;

    hipMemsetAsync(i_deg, 0, (size_t)N_ * 4, stream);

    // ---- conversions + wc + lambda + degree histogram/rank ----
    k_cvt<<<dim3((CVT_TOTAL_ + 255) / 256), dim3(256), 0, stream>>>(
        x, W_l1, att_l1, att_r1, W_l2, att_l2, att_r2, W_out, W_ff1, W_ff2,
        W_e1, att_e1, W_e2, att_e2, lq1, lk1, lq2, lk2, dst0,
        f_xb, w_l12t, w_outt, w_ff1t, w_ff2t, f_wc, f_lam, i_deg, i_rank);

    // ---- offsets ----
    k_scan<<<dim3(1), dim3(1024), 0, stream>>>(i_deg, i_offs);

    // ---- fused node-feature GEMM (x1,x2,al,ar in one pass) ----
    dim3 gA((N_ + 63) / 64, 1);
    k_gmm<0><<<gA, dim3(256), 0, stream>>>(f_xb, w_l12t, f_x12, N_, HC_, HC_,
        nullptr, nullptr, nullptr, nullptr, nullptr, f_all, f_arr);

    // ---- per-edge records + CSR fill ----
    k_et<<<dim3(E_ / 256), dim3(256), 0, stream>>>(eattr, f_all, f_arr, f_wc,
                                                   i_offs, i_rank, src0, dst0,
                                                   f_rec, i_csr);

    // ---- fused dual attention + combine + rmsnorm ----
    k_agg<<<dim3((N_ + 3) / 4), dim3(256), 0, stream>>>(
        f_x12, f_all, f_arr, f_rec, f_wc,
        W_e1, W_e2, f_lam, rms_attn, i_offs, i_csr, f_hnat);

    // ---- out projection + residual + fused layer-RMSNorm ----
    k_gmm<1><<<gA, dim3(256), 0, stream>>>(f_hnat, w_outt, f_h, N_, HC_, HC_,
        b_out, bias_x, x, rms_layer, f_hnat, nullptr, nullptr);

    // ---- fused FFN -> out ----
    k_ffn<<<gA, dim3(256), 0, stream>>>(f_hnat, w_ff1t, w_ff2t, b_ff1, b_ff2, f_h, out);
}

// Round 13
// 444.152 us; speedup vs baseline: 1.2650x; 1.2650x over previous
//
#include <hip/hip_runtime.h>
#include <math.h>

// Problem constants
constexpr int N_  = 50000;
constexpr int E_  = 800000;
constexpr int H_  = 8;
constexpr int C_  = 16;
constexpr int HC_ = 128;
constexpr int ED_ = 16;        // E_DIM
constexpr int FF_ = 512;
constexpr int NT_ = 3125;      // row tiles of 16 (50000 = 16*3125 exact)
constexpr float NEG_ = 0.2f;
constexpr float EPS_ = 1e-5f;
constexpr float LAMBDA_INIT_ = 0.8f;
constexpr float LOG2E_ = 1.4426950408889634f;

typedef __attribute__((ext_vector_type(8))) short bf16x8;
typedef __attribute__((ext_vector_type(4))) float f32x4;
typedef __fp16 half2v __attribute__((ext_vector_type(2)));

__device__ __forceinline__ float gelu_exact(float v) {
    return 0.5f * v * (1.0f + erff(v * 0.70710678118654752440f));
}
__device__ __forceinline__ ushort f2bf(float f) {  // RNE f32 -> bf16
    uint u = __float_as_uint(f);
    return (ushort)((u + 0x7FFFu + ((u >> 16) & 1u)) >> 16);
}
__device__ __forceinline__ ushort f2h(float f) {   // f32 -> f16 bits (RNE)
    __fp16 h = (__fp16)f;
    return *(ushort*)&h;
}
__device__ __forceinline__ uint pkh2(float a, float b) {  // 2xf32 -> packed f16x2
    half2v h = __builtin_amdgcn_cvt_pkrtz(a, b);
    return *(uint*)&h;
}
__device__ __forceinline__ void uph2(uint u, float& a, float& b) {
    half2v h = *(half2v*)&u;
    a = (float)h.x; b = (float)h.y;
}

// ---------------- consolidated conversion kernel (+ degree histogram) ----------------
constexpr int XC_   = N_ * HC_ / 4;   // float4 items
constexpr int WL12_ = 288 * 128;
constexpr int WO_   = 128 * 128;
constexpr int WF1_  = 512 * 128;
constexpr int WF2_  = 128 * 512;
constexpr int CVT_TOTAL_ = XC_ + WL12_ + WO_ + WF1_ + WF2_ + 128 + 8 + E_;

__device__ void wconv(const float* __restrict__ W, ushort* __restrict__ Wt, int t, int K, int N) {
    int col = t / K, k = t - col * K;
    Wt[t] = f2bf(W[(size_t)k * N + col]);
}
__device__ void wconv_h(const float* __restrict__ W, ushort* __restrict__ Wt, int t, int K, int N) {
    int col = t / K, k = t - col * K;
    Wt[t] = f2h(W[(size_t)k * N + col]);
}

__global__ __launch_bounds__(256) void k_cvt(const float* __restrict__ x,
        const float* __restrict__ Wl1, const float* __restrict__ al1w, const float* __restrict__ ar1w,
        const float* __restrict__ Wl2, const float* __restrict__ al2w, const float* __restrict__ ar2w,
        const float* __restrict__ Wout, const float* __restrict__ Wff1, const float* __restrict__ Wff2,
        const float* __restrict__ We1, const float* __restrict__ ae1,
        const float* __restrict__ We2, const float* __restrict__ ae2,
        const float* __restrict__ lq1, const float* __restrict__ lk1,
        const float* __restrict__ lq2, const float* __restrict__ lk2,
        const int* __restrict__ dst0,
        ushort* __restrict__ xb, ushort* __restrict__ wl12t,
        ushort* __restrict__ woutt, ushort* __restrict__ wff1t, ushort* __restrict__ wff2t,
        float2* __restrict__ wc, float* __restrict__ lam,
        int* __restrict__ deg, int* __restrict__ rank) {
    int g = blockIdx.x * blockDim.x + threadIdx.x;
    if (g < XC_) {
        float4 v = ((const float4*)x)[g];
        ushort4 o;
        o.x = f2bf(v.x); o.y = f2bf(v.y); o.z = f2bf(v.z); o.w = f2bf(v.w);
        ((ushort4*)xb)[g] = o;
        return;
    }
    g -= XC_;
    if (g < WL12_) {
        int col = g >> 7, k = g & 127;
        const float* W = (col < 144) ? Wl1 : Wl2;
        const float* alw = (col < 144) ? al1w : al2w;
        const float* arw = (col < 144) ? ar1w : ar2w;
        int c = (col < 144) ? col : col - 144;
        float v;
        if (c < 128) {
            v = W[(size_t)k * HC_ + c];
        } else if (c < 136) {
            int h = c - 128; v = 0.f;
#pragma unroll
            for (int cc = 0; cc < 16; ++cc) v = fmaf(W[(size_t)k * HC_ + h * 16 + cc], alw[h * 16 + cc], v);
        } else {
            int h = c - 136; v = 0.f;
#pragma unroll
            for (int cc = 0; cc < 16; ++cc) v = fmaf(W[(size_t)k * HC_ + h * 16 + cc], arw[h * 16 + cc], v);
        }
        wl12t[g] = f2bf(v);
        return;
    }
    g -= WL12_;
    if (g < WO_) { wconv(Wout, woutt, g, 128, 128); return; }
    g -= WO_;
    if (g < WF1_) { wconv(Wff1, wff1t, g, 128, 512); return; }
    g -= WF1_;
    if (g < WF2_) { wconv_h(Wff2, wff2t, g, 512, 128); return; }
    g -= WF2_;
    if (g < 128) {
        int k = g >> 3, h = g & 7;
        float s1 = 0.f, s2 = 0.f;
#pragma unroll
        for (int c = 0; c < 16; ++c) {
            s1 = fmaf(We1[k * HC_ + h * 16 + c], ae1[h * 16 + c], s1);
            s2 = fmaf(We2[k * HC_ + h * 16 + c], ae2[h * 16 + c], s2);
        }
        wc[g] = make_float2(s1, s2);
        return;
    }
    g -= 128;
    if (g < 8) {
        float d1 = 0.f, d2 = 0.f;
#pragma unroll
        for (int k = 0; k < 16; ++k) {
            d1 = fmaf(lq1[g * 16 + k], lk1[g * 16 + k], d1);
            d2 = fmaf(lq2[g * 16 + k], lk2[g * 16 + k], d2);
        }
        lam[g] = __expf(d1) - __expf(d2) + LAMBDA_INIT_;
        return;
    }
    g -= 8;
    if (g < E_) {
        rank[g] = atomicAdd(&deg[dst0[g]], 1);
    }
}

// ---------------- exclusive scan of deg -> offsets ----------------
__global__ __launch_bounds__(1024) void k_scan(const int* __restrict__ deg,
                                               int* __restrict__ offs) {
    __shared__ int part[1024];
    int t = threadIdx.x;
    const int CH = (N_ + 1023) / 1024;  // 49
    int b = t * CH;
    int e = min(N_, b + CH);
    int sum = 0;
    for (int i = b; i < e; ++i) sum += deg[i];
    part[t] = sum;
    __syncthreads();
    for (int off = 1; off < 1024; off <<= 1) {
        int v = (t >= off) ? part[t - off] : 0;
        __syncthreads();
        part[t] += v;
        __syncthreads();
    }
    int run = (t == 0) ? 0 : part[t - 1];
    for (int i = b; i < e; ++i) {
        offs[i] = run;
        run += deg[i];
    }
    if (t == 1023) offs[N_] = run;  // == E_
}

// ---------------- per-edge record builder + CSR fill ----------------
__global__ __launch_bounds__(256) void k_et(const float* __restrict__ eattr,
                                            const float2* __restrict__ all_,
                                            const float2* __restrict__ arr_,
                                            const float2* __restrict__ wc,
                                            const int* __restrict__ offs,
                                            const int* __restrict__ rank,
                                            const int* __restrict__ src0,
                                            const int* __restrict__ dst0,
                                            uint* __restrict__ rec,
                                            int* __restrict__ csr_src) {
    __shared__ float2 wcs[128];
    int t = threadIdx.x;
    if (t < 128) wcs[t] = wc[t];
    __syncthreads();
    int e = blockIdx.x * blockDim.x + t;
    if (e >= E_) return;
    const float* ea = eattr + (size_t)e * ED_;
    float eav[16];
    {
        float4 q0 = *(const float4*)(ea + 0);
        float4 q1 = *(const float4*)(ea + 4);
        float4 q2 = *(const float4*)(ea + 8);
        float4 q3 = *(const float4*)(ea + 12);
        eav[0] = q0.x; eav[1] = q0.y; eav[2] = q0.z; eav[3] = q0.w;
        eav[4] = q1.x; eav[5] = q1.y; eav[6] = q1.z; eav[7] = q1.w;
        eav[8] = q2.x; eav[9] = q2.y; eav[10] = q2.z; eav[11] = q2.w;
        eav[12] = q3.x; eav[13] = q3.y; eav[14] = q3.z; eav[15] = q3.w;
    }
    int src = src0[e], dst = dst0[e];
    const float2* alp = all_ + (size_t)dst * 8;
    const float2* arp = arr_ + (size_t)src * 8;
    uint ra[8], re[8];
#pragma unroll
    for (int h = 0; h < 8; ++h) {
        float t1 = 0.f, t2 = 0.f;
#pragma unroll
        for (int k = 0; k < 16; ++k) {
            float2 w = wcs[k * 8 + h];
            t1 = fmaf(eav[k], w.x, t1);
            t2 = fmaf(eav[k], w.y, t2);
        }
        float2 al = alp[h], ar = arp[h];
        float a1 = al.x + ar.x + t1;
        a1 = ((a1 >= 0.f) ? a1 : NEG_ * a1) * LOG2E_;
        float a2 = al.y + ar.y + t2;
        a2 = ((a2 >= 0.f) ? a2 : NEG_ * a2) * LOG2E_;
        ra[h] = pkh2(a1, a2);
    }
#pragma unroll
    for (int i = 0; i < 8; ++i) re[i] = pkh2(eav[2 * i], eav[2 * i + 1]);
    int p = offs[dst] + rank[e];
    csr_src[p] = src;
    uint4* rp = (uint4*)(rec + (size_t)p * 16);
    rp[0] = make_uint4(ra[0], ra[1], ra[2], ra[3]);
    rp[1] = make_uint4(ra[4], ra[5], ra[6], ra[7]);
    rp[2] = make_uint4(re[0], re[1], re[2], re[3]);
    rp[3] = make_uint4(re[4], re[5], re[6], re[7]);
}

// ---------------- fused dual attention + diff combine + rmsnorm (unchanged) ----------------
__global__ __launch_bounds__(256) void k_agg(const ushort* __restrict__ x12,
                                             const float2* __restrict__ all_,
                                             const float2* __restrict__ arr_,
                                             const uint* __restrict__ rec,
                                             const float2* __restrict__ wcg,
                                             const float* __restrict__ We1, const float* __restrict__ We2,
                                             const float* __restrict__ lam, const float* __restrict__ rms_attn,
                                             const int* __restrict__ offs, const int* __restrict__ csr_src,
                                             ushort* __restrict__ attn_out) {
    int wid = (int)((blockIdx.x * blockDim.x + threadIdx.x) >> 6);
    if (wid >= N_) return;
    int lane = threadIdx.x & 63;
    int h = lane >> 3;
    int cp = lane & 7;
    int e0 = h * C_ + cp * 2;
    int hbase = lane & 56;

    int s = offs[wid], eend = offs[wid + 1];
    int deg = eend - s;

    float s1 = 0.f, s2 = 0.f;
    float ax1x = 0.f, ax1y = 0.f, ax2x = 0.f, ax2y = 0.f;
    float ws1x = 0.f, ws1y = 0.f, ws2x = 0.f, ws2y = 0.f;
    float esx = 0.f, esy = 0.f;

    auto edge_step = [&](int j) {
        int src = csr_src[j];
        const uint* r = rec + (size_t)j * 16;
        uint ua = r[h];
        uint ue = r[8 + cp];
        uint2 ux = *(const uint2*)(x12 + (size_t)src * 256 + e0 * 2);
        float a1, a2, eax, eay, x1a, x2a, x1b, x2b;
        uph2(ua, a1, a2);
        uph2(ue, eax, eay);
        uph2(ux.x, x1a, x2a);
        uph2(ux.y, x1b, x2b);
        float p1 = exp2f(a1), p2 = exp2f(a2);
        s1 += p1; s2 += p2;
        ax1x = fmaf(p1, x1a, ax1x); ax1y = fmaf(p1, x1b, ax1y);
        ax2x = fmaf(p2, x2a, ax2x); ax2y = fmaf(p2, x2b, ax2y);
        ws1x = fmaf(p1, eax, ws1x); ws1y = fmaf(p1, eay, ws1y);
        ws2x = fmaf(p2, eax, ws2x); ws2y = fmaf(p2, eay, ws2y);
        esx += eax; esy += eay;
    };

    int j = s;
    for (; j + 1 < eend; j += 2) {
        edge_step(j);
        edge_step(j + 1);
    }
    if (j < eend) edge_step(j);

    float invdeg = 1.0f / (float)max(deg, 1);
    float esmx = esx * invdeg, esmy = esy * invdeg;

    float2 w0 = wcg[(2 * cp) * 8 + h];
    float2 w1 = wcg[(2 * cp + 1) * 8 + h];
    float tp1 = esmx * w0.x + esmy * w1.x;
    float tp2 = esmx * w0.y + esmy * w1.y;
    tp1 += __shfl_xor(tp1, 1); tp1 += __shfl_xor(tp1, 2); tp1 += __shfl_xor(tp1, 4);
    tp2 += __shfl_xor(tp2, 1); tp2 += __shfl_xor(tp2, 2); tp2 += __shfl_xor(tp2, 4);

    float2 alv = all_[(size_t)wid * 8 + h];
    float2 arv = arr_[(size_t)wid * 8 + h];
    float aS1 = alv.x + arv.x + tp1;
    aS1 = ((aS1 >= 0.f) ? aS1 : NEG_ * aS1) * LOG2E_;
    float aS2 = alv.y + arv.y + tp2;
    aS2 = ((aS2 >= 0.f) ? aS2 : NEG_ * aS2) * LOG2E_;
    float pS1 = exp2f(aS1), pS2 = exp2f(aS2);
    {
        uint2 ux = *(const uint2*)(x12 + (size_t)wid * 256 + e0 * 2);
        float x1a, x2a, x1b, x2b;
        uph2(ux.x, x1a, x2a);
        uph2(ux.y, x1b, x2b);
        s1 += pS1; s2 += pS2;
        ax1x = fmaf(pS1, x1a, ax1x); ax1y = fmaf(pS1, x1b, ax1y);
        ax2x = fmaf(pS2, x2a, ax2x); ax2y = fmaf(pS2, x2b, ax2y);
        ws1x = fmaf(pS1, esmx, ws1x); ws1y = fmaf(pS1, esmy, ws1y);
        ws2x = fmaf(pS2, esmx, ws2x); ws2y = fmaf(pS2, esmy, ws2y);
    }

    float o1x = ax1x, o1y = ax1y, o2x = ax2x, o2y = ax2y;
#pragma unroll
    for (int kp = 0; kp < 8; ++kp) {
        float wa1 = __shfl(ws1x, hbase + kp), wb1 = __shfl(ws1y, hbase + kp);
        float wa2 = __shfl(ws2x, hbase + kp), wb2 = __shfl(ws2y, hbase + kp);
        float2 a0 = *(const float2*)(We1 + (2 * kp) * HC_ + e0);
        float2 a1 = *(const float2*)(We1 + (2 * kp + 1) * HC_ + e0);
        float2 b0 = *(const float2*)(We2 + (2 * kp) * HC_ + e0);
        float2 b1 = *(const float2*)(We2 + (2 * kp + 1) * HC_ + e0);
        o1x = fmaf(wa1, a0.x, o1x); o1x = fmaf(wb1, a1.x, o1x);
        o1y = fmaf(wa1, a0.y, o1y); o1y = fmaf(wb1, a1.y, o1y);
        o2x = fmaf(wa2, b0.x, o2x); o2x = fmaf(wb2, b1.x, o2x);
        o2y = fmaf(wa2, b0.y, o2y); o2y = fmaf(wb2, b1.y, o2y);
    }
    float inv1 = 1.0f / s1, inv2 = 1.0f / s2;
    o1x *= inv1; o1y *= inv1; o2x *= inv2; o2y *= inv2;

    float lamh = lam[h];
    float v0 = o1x - lamh * o2x;
    float v1 = o1y - lamh * o2y;

    float ss = v0 * v0 + v1 * v1;
#pragma unroll
    for (int mk = 1; mk < 64; mk <<= 1) ss += __shfl_xor(ss, mk);
    float rn = rsqrtf(ss * (1.0f / 128.0f) + EPS_);
    float g0 = rms_attn[e0] * (1.0f - LAMBDA_INIT_);
    float g1 = rms_attn[e0 + 1] * (1.0f - LAMBDA_INIT_);
    ushort2 o;
    o.x = f2bf(v0 * rn * g0);
    o.y = f2bf(v1 * rn * g1);
    *(ushort2*)(attn_out + (size_t)wid * HC_ + e0) = o;
}

// ---------------- persistent node-feature GEMM: x12 + al/ar ----------------
// 4 waves: cg = w&1 selects 9 of 18 B-cols (pass 1 or 2); rh = w>>1 row stream.
// B fragments hoisted into registers once; loop over 16-row tiles.
__global__ __launch_bounds__(256) void k_g0(const ushort* __restrict__ xb,
                                            const ushort* __restrict__ wl12t,
                                            ushort* __restrict__ x12,   // [N][256]: (x1[c],x2[c]) f16 pairs
                                            float* __restrict__ alr,
                                            float* __restrict__ arr) {
    int tid = threadIdx.x;
    int w = tid >> 6, lane = tid & 63;
    int lrow = lane & 15, kg = lane >> 4;
    int cg = w & 1, rh = w >> 1;

    bf16x8 B[9][4];
#pragma unroll
    for (int c = 0; c < 9; ++c) {
        int ct = cg * 9 + c;
#pragma unroll
        for (int ks = 0; ks < 4; ++ks)
            B[c][ks] = *(const bf16x8*)(wl12t + (size_t)(ct * 16 + lrow) * 128 + ks * 32 + kg * 8);
    }

    for (int tile = blockIdx.x * 2 + rh; tile < NT_; tile += gridDim.x * 2) {
        int r0 = tile * 16;
        const ushort* Ap = xb + (size_t)(r0 + lrow) * 128 + kg * 8;
        bf16x8 af[4];
#pragma unroll
        for (int ks = 0; ks < 4; ++ks) af[ks] = *(const bf16x8*)(Ap + ks * 32);
        f32x4 acc[9];
#pragma unroll
        for (int c = 0; c < 9; ++c) acc[c] = (f32x4){0.f, 0.f, 0.f, 0.f};
#pragma unroll
        for (int ks = 0; ks < 4; ++ks)
#pragma unroll
            for (int c = 0; c < 9; ++c)
                acc[c] = __builtin_amdgcn_mfma_f32_16x16x32_bf16(af[ks], B[c][ks], acc[c], 0, 0, 0);

        // features: ushort store (x-pass interleaved at element granularity)
#pragma unroll
        for (int c = 0; c < 8; ++c) {
            int col = c * 16 + lrow;
#pragma unroll
            for (int jj = 0; jj < 4; ++jj) {
                int r = r0 + kg * 4 + jj;
                x12[(size_t)r * 256 + col * 2 + cg] = f2h(acc[c][jj]);
            }
        }
        // al/ar u-columns
#pragma unroll
        for (int jj = 0; jj < 4; ++jj) {
            int r = r0 + kg * 4 + jj;
            float v = acc[8][jj];
            if (lrow < 8) alr[((size_t)r * 8 + lrow) * 2 + cg] = v;
            else          arr[((size_t)r * 8 + (lrow - 8)) * 2 + cg] = v;
        }
    }
}

// ---------------- persistent out-proj GEMM + residual + fused RMSNorm ----------------
__global__ __launch_bounds__(256) void k_g1(const ushort* __restrict__ attn,   // [N][128] bf16
                                            const ushort* __restrict__ woutt,  // [128][128] bf16
                                            const float* __restrict__ b1,
                                            const float* __restrict__ b2,
                                            const float* __restrict__ res,     // x f32
                                            const float* __restrict__ scale,
                                            float* __restrict__ hbuf,          // f32 out
                                            ushort* __restrict__ hn) {         // bf16 normed out
    int tid = threadIdx.x;
    int w = tid >> 6, lane = tid & 63;
    int lrow = lane & 15, kg = lane >> 4;

    bf16x8 B[8][4];
#pragma unroll
    for (int c = 0; c < 8; ++c)
#pragma unroll
        for (int ks = 0; ks < 4; ++ks)
            B[c][ks] = *(const bf16x8*)(woutt + (size_t)(c * 16 + lrow) * 128 + ks * 32 + kg * 8);

    for (int tile = blockIdx.x * 4 + w; tile < NT_; tile += gridDim.x * 4) {
        int r0 = tile * 16;
        const ushort* Ap = attn + (size_t)(r0 + lrow) * 128 + kg * 8;
        bf16x8 af[4];
#pragma unroll
        for (int ks = 0; ks < 4; ++ks) af[ks] = *(const bf16x8*)(Ap + ks * 32);
        f32x4 acc[8];
#pragma unroll
        for (int c = 0; c < 8; ++c) acc[c] = (f32x4){0.f, 0.f, 0.f, 0.f};
#pragma unroll
        for (int ks = 0; ks < 4; ++ks)
#pragma unroll
            for (int c = 0; c < 8; ++c)
                acc[c] = __builtin_amdgcn_mfma_f32_16x16x32_bf16(af[ks], B[c][ks], acc[c], 0, 0, 0);

        float ssj[4] = {0.f, 0.f, 0.f, 0.f};
#pragma unroll
        for (int c = 0; c < 8; ++c) {
            int col = c * 16 + lrow;
            float bv = b1[col] + b2[col];
#pragma unroll
            for (int jj = 0; jj < 4; ++jj) {
                int r = r0 + kg * 4 + jj;
                float v = acc[c][jj] + bv + res[(size_t)r * HC_ + col];
                acc[c][jj] = v;
                ssj[jj] += v * v;
            }
        }
        float rn[4];
#pragma unroll
        for (int jj = 0; jj < 4; ++jj) {
            float ss = ssj[jj];
            ss += __shfl_xor(ss, 1); ss += __shfl_xor(ss, 2);
            ss += __shfl_xor(ss, 4); ss += __shfl_xor(ss, 8);
            rn[jj] = rsqrtf(ss * (1.0f / 128.0f) + EPS_);
        }
#pragma unroll
        for (int c = 0; c < 8; ++c) {
            int col = c * 16 + lrow;
            float sc = scale[col];
#pragma unroll
            for (int jj = 0; jj < 4; ++jj) {
                int r = r0 + kg * 4 + jj;
                float v = acc[c][jj];
                hbuf[(size_t)r * HC_ + col] = v;
                hn[(size_t)r * HC_ + col] = f2bf(v * rn[jj] * sc);
            }
        }
    }
}

// ---------------- persistent ff1: g = gelu(hn @ Wff1 + b1), f16 out ----------------
// wave w owns col strip w*128..+127 (8 ct); B hoisted (32 frags).
__global__ __launch_bounds__(256) void k_ff1(const ushort* __restrict__ hn,     // [N][128] bf16
                                             const ushort* __restrict__ wff1t,  // [512][128] bf16
                                             const float* __restrict__ bff1,
                                             ushort* __restrict__ g) {          // [N][512] f16
    int tid = threadIdx.x;
    int w = tid >> 6, lane = tid & 63;
    int lrow = lane & 15, kg = lane >> 4;

    bf16x8 B[8][4];
#pragma unroll
    for (int c = 0; c < 8; ++c)
#pragma unroll
        for (int ks = 0; ks < 4; ++ks)
            B[c][ks] = *(const bf16x8*)(wff1t + (size_t)(w * 128 + c * 16 + lrow) * 128 + ks * 32 + kg * 8);

    for (int tile = blockIdx.x; tile < NT_; tile += gridDim.x) {
        int r0 = tile * 16;
        const ushort* Ap = hn + (size_t)(r0 + lrow) * 128 + kg * 8;
        bf16x8 af[4];
#pragma unroll
        for (int ks = 0; ks < 4; ++ks) af[ks] = *(const bf16x8*)(Ap + ks * 32);
        f32x4 acc[8];
#pragma unroll
        for (int c = 0; c < 8; ++c) acc[c] = (f32x4){0.f, 0.f, 0.f, 0.f};
#pragma unroll
        for (int ks = 0; ks < 4; ++ks)
#pragma unroll
            for (int c = 0; c < 8; ++c)
                acc[c] = __builtin_amdgcn_mfma_f32_16x16x32_bf16(af[ks], B[c][ks], acc[c], 0, 0, 0);

#pragma unroll
        for (int c = 0; c < 8; ++c) {
            int col = w * 128 + c * 16 + lrow;
            float bv = bff1[col];
#pragma unroll
            for (int jj = 0; jj < 4; ++jj) {
                float v = gelu_exact(acc[c][jj] + bv);
                float other = __shfl_xor(v, 1);
                if (!(lrow & 1)) {
                    int r = r0 + kg * 4 + jj;
                    ((uint*)g)[(size_t)r * 256 + (col >> 1)] = pkh2(v, other);
                }
            }
        }
    }
}

// ---------------- persistent ff2: out = h + g @ Wff2 + b2 (f16 MFMA, K=512) ----------------
// wave w owns cols {2w,2w+1}*16 (2 ct); B hoisted (32 frags).
__global__ __launch_bounds__(256) void k_ff2(const ushort* __restrict__ g,      // [N][512] f16
                                             const ushort* __restrict__ wff2t,  // [128][512] f16
                                             const float* __restrict__ bff2,
                                             const float* __restrict__ hres,    // f32
                                             float* __restrict__ out) {
    int tid = threadIdx.x;
    int w = tid >> 6, lane = tid & 63;
    int lrow = lane & 15, kg = lane >> 4;

    bf16x8 B[2][16];
#pragma unroll
    for (int c = 0; c < 2; ++c)
#pragma unroll
        for (int ks = 0; ks < 16; ++ks)
            B[c][ks] = *(const bf16x8*)(wff2t + (size_t)((2 * w + c) * 16 + lrow) * 512 + ks * 32 + kg * 8);

    for (int tile = blockIdx.x; tile < NT_; tile += gridDim.x) {
        int r0 = tile * 16;
        const ushort* Ap = g + (size_t)(r0 + lrow) * 512 + kg * 8;
        f32x4 acc[2];
        acc[0] = (f32x4){0.f, 0.f, 0.f, 0.f};
        acc[1] = (f32x4){0.f, 0.f, 0.f, 0.f};
#pragma unroll
        for (int ks = 0; ks < 16; ++ks) {
            bf16x8 af = *(const bf16x8*)(Ap + ks * 32);
            acc[0] = __builtin_amdgcn_mfma_f32_16x16x32_f16(af, B[0][ks], acc[0], 0, 0, 0);
            acc[1] = __builtin_amdgcn_mfma_f32_16x16x32_f16(af, B[1][ks], acc[1], 0, 0, 0);
        }
#pragma unroll
        for (int c = 0; c < 2; ++c) {
            int col = (2 * w + c) * 16 + lrow;
            float bv = bff2[col];
#pragma unroll
            for (int jj = 0; jj < 4; ++jj) {
                int r = r0 + kg * 4 + jj;
                out[(size_t)r * HC_ + col] = acc[c][jj] + bv + hres[(size_t)r * HC_ + col];
            }
        }
    }
}

extern "C" void kernel_launch(void* const* d_in, const int* in_sizes, int n_in,
                              void* d_out, int out_size, void* d_ws, size_t ws_size,
                              hipStream_t stream) {
    const float* x        = (const float*)d_in[0];
    const float* eattr    = (const float*)d_in[1];
    const float* W_l1     = (const float*)d_in[2];
    const float* W_l2     = (const float*)d_in[3];
    const float* att_l1   = (const float*)d_in[4];
    const float* att_r1   = (const float*)d_in[5];
    const float* att_l2   = (const float*)d_in[6];
    const float* att_r2   = (const float*)d_in[7];
    const float* W_e1     = (const float*)d_in[8];
    const float* att_e1   = (const float*)d_in[9];
    const float* W_e2     = (const float*)d_in[10];
    const float* att_e2   = (const float*)d_in[11];
    const float* lq1      = (const float*)d_in[12];
    const float* lk1      = (const float*)d_in[13];
    const float* lq2      = (const float*)d_in[14];
    const float* lk2      = (const float*)d_in[15];
    const float* rms_attn = (const float*)d_in[16];
    const float* W_out    = (const float*)d_in[17];
    const float* b_out    = (const float*)d_in[18];
    const float* bias_x   = (const float*)d_in[19];
    const float* rms_layer= (const float*)d_in[20];
    const float* W_ff1    = (const float*)d_in[21];
    const float* b_ff1    = (const float*)d_in[22];
    const float* W_ff2    = (const float*)d_in[23];
    const float* b_ff2    = (const float*)d_in[24];
    const int*   eidx     = (const int*)d_in[25];
    const int* src0 = eidx;
    const int* dst0 = eidx + E_;
    float* out = (float*)d_out;

    // ---- workspace layout ----
    char* base = (char*)d_ws;
    size_t off = 0;
    auto alloc = [&](size_t bytes) -> char* {
        off = (off + 255) & ~(size_t)255;
        char* p = base + off;
        off += bytes;
        return p;
    };
    const size_t NF = (size_t)N_ * HC_;
    float*  f_h    = (float*)alloc(NF * 4);
    ushort* f_hnat = (ushort*)alloc(NF * 2);        // attn bf16 then hn bf16
    ushort* f_x12  = (ushort*)alloc(NF * 2 * 2);    // interleaved f16 x1/x2 [N][256]
    char*   f_rg   = alloc((size_t)E_ * 64);        // rec (64B/edge) then g [N][512] f16
    uint*   f_rec  = (uint*)f_rg;
    ushort* f_g    = (ushort*)f_rg;
    ushort* f_xb   = (ushort*)alloc(NF * 2);
    ushort* w_l12t = (ushort*)alloc((size_t)288 * 128 * 2);
    ushort* w_outt = (ushort*)alloc((size_t)HC_ * HC_ * 2);
    ushort* w_ff1t = (ushort*)alloc((size_t)HC_ * FF_ * 2);
    ushort* w_ff2t = (ushort*)alloc((size_t)FF_ * HC_ * 2);
    float2* f_all  = (float2*)alloc((size_t)N_ * H_ * 8);
    float2* f_arr  = (float2*)alloc((size_t)N_ * H_ * 8);
    float2* f_wc   = (float2*)alloc(128 * 8);
    float*  f_lam  = (float*)alloc(256);
    int*  i_deg  = (int*)alloc((size_t)N_ * 4);
    int*  i_offs = (int*)alloc((size_t)(N_ + 1) * 4);
    int*  i_rank = (int*)alloc((size_t)E_ * 4);
    int*  i_csr  = (int*)alloc((size_t)E_ * 4);
    (void)ws_size;

    hipMemsetAsync(i_deg, 0, (size_t)N_ * 4, stream);

    // ---- conversions + wc + lambda + degree histogram/rank ----
    k_cvt<<<dim3((CVT_TOTAL_ + 255) / 256), dim3(256), 0, stream>>>(
        x, W_l1, att_l1, att_r1, W_l2, att_l2, att_r2, W_out, W_ff1, W_ff2,
        W_e1, att_e1, W_e2, att_e2, lq1, lk1, lq2, lk2, dst0,
        f_xb, w_l12t, w_outt, w_ff1t, w_ff2t, f_wc, f_lam, i_deg, i_rank);

    // ---- offsets ----
    k_scan<<<dim3(1), dim3(1024), 0, stream>>>(i_deg, i_offs);

    // ---- persistent node-feature GEMM ----
    k_g0<<<dim3(512), dim3(256), 0, stream>>>(f_xb, w_l12t, f_x12,
                                              (float*)f_all, (float*)f_arr);

    // ---- per-edge records + CSR fill ----
    k_et<<<dim3(E_ / 256), dim3(256), 0, stream>>>(eattr, f_all, f_arr, f_wc,
                                                   i_offs, i_rank, src0, dst0,
                                                   f_rec, i_csr);

    // ---- fused dual attention + combine + rmsnorm ----
    k_agg<<<dim3((N_ + 3) / 4), dim3(256), 0, stream>>>(
        f_x12, f_all, f_arr, f_rec, f_wc,
        W_e1, W_e2, f_lam, rms_attn, i_offs, i_csr, f_hnat);

    // ---- persistent out-proj + residual + RMSNorm ----
    k_g1<<<dim3(256), dim3(256), 0, stream>>>(f_hnat, w_outt, b_out, bias_x, x,
                                              rms_layer, f_h, f_hnat);

    // ---- persistent FFN (g aliases dead rec) ----
    k_ff1<<<dim3(512), dim3(256), 0, stream>>>(f_hnat, w_ff1t, b_ff1, f_g);
    k_ff2<<<dim3(1024), dim3(256), 0, stream>>>(f_g, w_ff2t, b_ff2, f_h, out);
}